// Round 1
// baseline (1161.870 us; speedup 1.0000x reference)
//
#include <hip/hip_runtime.h>
#include <math.h>

#define B_ 4
#define C_ 64
#define M_ 8
#define H_ 224
#define W_ 224
#define N_ (H_*W_)        // 50176
#define CN_ (C_*N_)       // 3211264
#define MN_ (M_*N_)       // 401408
#define BCN_ (B_*CN_)
#define BMN_ (B_*MN_)

__device__ __forceinline__ float relu6f(float v){ return fminf(fmaxf(v,0.0f),6.0f); }
__device__ __forceinline__ float softplusf(float v){
  return v > 0.0f ? v + log1pf(expf(-v)) : log1pf(expf(v));
}

#define FMA4(A, W, X) { A.x = fmaf((W), (X).x, A.x); A.y = fmaf((W), (X).y, A.y); \
                        A.z = fmaf((W), (X).z, A.z); A.w = fmaf((W), (X).w, A.w); }

// ---------------------------------------------------------------------------
// K1: h = relu6(bn(conv1x1(x))) AND K = softplus(conv1x1(x)+kb) AND Ksum
// 128-px tile, 64 oc/block. c in 8-wide slabs double-buffered in LDS.
// Thread = 4 px x 8 oc (och = 2*wave + lane/32) + 1 K-row (m = och).
// NEW: Ksum reduced in epilogue (half-wave shuffle + 1 atomic) so K4 dies.
// ---------------------------------------------------------------------------
__global__ __launch_bounds__(256) void k_fc1k(const float* __restrict__ x,
                                              const float* __restrict__ w,
                                              const float* __restrict__ bn,
                                              const float* __restrict__ kw,
                                              const float* __restrict__ kb,
                                              float* __restrict__ h,
                                              float* __restrict__ Kq,
                                              float* __restrict__ Ksum)
{
  __shared__ float xsl[2*1024];   // [buf][c'(8)][px(128)]
  __shared__ float wl [2*512];    // [buf][c'(8)][oc(64)]
  __shared__ float kt [512];      // [c(64)][m(8)]
  const int tid  = threadIdx.x;
  const int b    = blockIdx.x / 392;
  const int pg   = blockIdx.x % 392;
  const int pix0 = pg*128;
  const float* xb = x + (size_t)b*CN_ + pix0;

  for (int idx = tid; idx < 512; idx += 256) {
    const int c = idx >> 3, m = idx & 7;
    kt[idx] = kw[m*64 + c];
  }

  // staging roles
  const int scp = tid >> 5;            // c' 0..7
  const int spx = (tid & 31) << 2;     // px 0,4,..,124
  const int e0 = tid*2, e1 = tid*2+1;
  const int wc0 = e0 >> 6, wo0 = e0 & 63;
  const int wc1 = e1 >> 6, wo1 = e1 & 63;

  { // stage slab 0
    const float4 xr = *(const float4*)(xb + (size_t)scp*N_ + spx);
    const float w0r = w[wo0*64 + wc0];
    const float w1r = w[wo1*64 + wc1];
    *(float4*)&xsl[scp*128 + spx] = xr;
    wl[e0] = w0r; wl[e1] = w1r;
  }
  __syncthreads();

  const int lane = tid & 63, wv_ = tid >> 6;
  const int och  = 2*wv_ + (lane >> 5);   // 0..7
  const int ocb  = och*8;
  const int px4  = (lane & 31) << 2;

  float4 ah[8];
  float4 ak = {0,0,0,0};
  #pragma unroll
  for (int i = 0; i < 8; ++i) ah[i] = make_float4(0.f,0.f,0.f,0.f);

  for (int ck = 0; ck < 8; ++ck) {
    const int cur = ck & 1, nxt = cur ^ 1;
    const float* xc = &xsl[cur*1024];
    const float* wc = &wl[cur*512];
    float4 xr; float w0r, w1r;
    if (ck < 7) {                       // issue next slab's global loads now
      const int c0n = (ck+1)*8;
      xr  = *(const float4*)(xb + (size_t)(c0n + scp)*N_ + spx);
      w0r = w[wo0*64 + c0n + wc0];
      w1r = w[wo1*64 + c0n + wc1];
    }
    #pragma unroll
    for (int cp = 0; cp < 8; ++cp) {
      const float4 xv = *(const float4*)&xc[cp*128 + px4];
      const float4 w0 = *(const float4*)&wc[cp*64 + ocb];
      const float4 w1 = *(const float4*)&wc[cp*64 + ocb + 4];
      const float kvw = kt[(ck*8+cp)*8 + och];
      FMA4(ah[0], w0.x, xv); FMA4(ah[1], w0.y, xv);
      FMA4(ah[2], w0.z, xv); FMA4(ah[3], w0.w, xv);
      FMA4(ah[4], w1.x, xv); FMA4(ah[5], w1.y, xv);
      FMA4(ah[6], w1.z, xv); FMA4(ah[7], w1.w, xv);
      FMA4(ak, kvw, xv);
    }
    if (ck < 7) {                       // park staged regs into next buffer
      *(float4*)&xsl[nxt*1024 + scp*128 + spx] = xr;
      wl[nxt*512 + e0] = w0r; wl[nxt*512 + e1] = w1r;
    }
    __syncthreads();
  }

  float* hb = h + (size_t)b*CN_ + pix0 + px4;
  #pragma unroll
  for (int o = 0; o < 8; ++o) {
    const int oc = ocb + o;
    const float inv  = bn[oc] / sqrtf(bn[192+oc] + 1e-5f);
    const float beta = bn[64+oc] - bn[128+oc]*inv;
    float4 o4;
    o4.x = relu6f(fmaf(ah[o].x, inv, beta));
    o4.y = relu6f(fmaf(ah[o].y, inv, beta));
    o4.z = relu6f(fmaf(ah[o].z, inv, beta));
    o4.w = relu6f(fmaf(ah[o].w, inv, beta));
    *(float4*)(hb + (size_t)oc*N_) = o4;
  }
  { // K row m = och, plus Ksum partial (sum over this block's 128 px)
    const float kbm = kb[och];
    float4 q;
    q.x = softplusf(ak.x + kbm); q.y = softplusf(ak.y + kbm);
    q.z = softplusf(ak.z + kbm); q.w = softplusf(ak.w + kbm);
    *(float4*)(Kq + (size_t)b*MN_ + (size_t)och*N_ + pix0 + px4) = q;
    float ss = (q.x + q.y) + (q.z + q.w);
    ss += __shfl_xor(ss, 1);
    ss += __shfl_xor(ss, 2);
    ss += __shfl_xor(ss, 4);
    ss += __shfl_xor(ss, 8);
    ss += __shfl_xor(ss, 16);
    if ((lane & 31) == 0) atomicAdd(&Ksum[b*8 + och], ss);
  }
}

// ---------------------------------------------------------------------------
// K2: s = relu6(bn1(dw5x5(h))) + relu6(bn2(dw3x3(h)))   32x32 tile per (b,c)
// ---------------------------------------------------------------------------
__global__ __launch_bounds__(256) void k_dw(const float* __restrict__ h,
                                            const float* __restrict__ w5,
                                            const float* __restrict__ w3,
                                            const float* __restrict__ bn1,
                                            const float* __restrict__ bn2,
                                            float* __restrict__ s)
{
  __shared__ float tile[36*37];
  const int tid = threadIdx.x;
  const int blk = blockIdx.x;              // B*C*49
  const int t   = blk % 49;
  const int bc  = blk / 49;
  const int c   = bc & 63;
  const int tx0 = (t % 7) * 32;
  const int ty0 = (t / 7) * 32;
  const float* hb = h + (size_t)bc * N_;

  for (int idx = tid; idx < 1296; idx += 256) {
    const int ly = idx / 36, lx = idx - ly*36;
    const int gy = ty0 + ly - 2, gx = tx0 + lx - 2;
    float v = 0.0f;
    if (gy >= 0 && gy < H_ && gx >= 0 && gx < W_) v = hb[gy*W_ + gx];
    tile[ly*37 + lx] = v;
  }
  __syncthreads();

  float w5r[25], w3r[9];
  #pragma unroll
  for (int i = 0; i < 25; ++i) w5r[i] = w5[c*25 + i];
  #pragma unroll
  for (int i = 0; i < 9; ++i)  w3r[i] = w3[c*9 + i];
  const float inv1 = bn1[c] / sqrtf(bn1[192+c] + 1e-5f);
  const float bet1 = bn1[64+c] - bn1[128+c]*inv1;
  const float inv2 = bn2[c] / sqrtf(bn2[192+c] + 1e-5f);
  const float bet2 = bn2[64+c] - bn2[128+c]*inv2;

  const int ty  = tid >> 3;
  const int tx4 = (tid & 7) << 2;
  float a5[4] = {0,0,0,0}, a3[4] = {0,0,0,0};
  #pragma unroll
  for (int dy = 0; dy < 5; ++dy) {
    float r[8];
    #pragma unroll
    for (int i = 0; i < 8; ++i) r[i] = tile[(ty+dy)*37 + tx4 + i];
    #pragma unroll
    for (int dx = 0; dx < 5; ++dx) {
      const float wv = w5r[dy*5+dx];
      #pragma unroll
      for (int p = 0; p < 4; ++p) a5[p] = fmaf(wv, r[p+dx], a5[p]);
    }
    if (dy >= 1 && dy <= 3) {
      #pragma unroll
      for (int dx = 1; dx <= 3; ++dx) {
        const float wv = w3r[(dy-1)*3+(dx-1)];
        #pragma unroll
        for (int p = 0; p < 4; ++p) a3[p] = fmaf(wv, r[p+dx], a3[p]);
      }
    }
  }
  float* sb = s + (size_t)bc * N_ + (ty0+ty)*W_ + tx0 + tx4;
  float4 o4;
  o4.x = relu6f(fmaf(a5[0],inv1,bet1)) + relu6f(fmaf(a3[0],inv2,bet2));
  o4.y = relu6f(fmaf(a5[1],inv1,bet1)) + relu6f(fmaf(a3[1],inv2,bet2));
  o4.z = relu6f(fmaf(a5[2],inv1,bet1)) + relu6f(fmaf(a3[2],inv2,bet2));
  o4.w = relu6f(fmaf(a5[3],inv1,bet1)) + relu6f(fmaf(a3[3],inv2,bet2));
  *(float4*)sb = o4;
}

// ---------------------------------------------------------------------------
// K3 (fused K3+K4): V = conv1x1(x,v_w)+v_b + relu6(bn(conv1x1(s,fc2_w)))
// then KV[b,m,c] += sum over this block's 128 px of K[m,px]*V[c,px].
// V never touches global memory. K tile (8x128 = 4KB) staged into reused xsl.
// Reduction: per-thread 4-px dots, then value-halving butterfly across the
// 32-lane half-wave (62 shuffles) -> 2 atomicAdds per thread.
// ---------------------------------------------------------------------------
__global__ __launch_bounds__(256) void k_vkv(const float* __restrict__ x,
                                             const float* __restrict__ s,
                                             const float* __restrict__ vw,
                                             const float* __restrict__ vb,
                                             const float* __restrict__ fw,
                                             const float* __restrict__ fbn,
                                             const float* __restrict__ Kq,
                                             float* __restrict__ KV)
{
  __shared__ float xsl[2*1024];
  __shared__ float ssl[2*1024];
  __shared__ float wvl[2*512];
  __shared__ float wfl[2*512];
  const int tid  = threadIdx.x;
  const int b    = blockIdx.x / 392;
  const int pg   = blockIdx.x % 392;
  const int pix0 = pg*128;
  const float* xb = x + (size_t)b*CN_ + pix0;
  const float* sb = s + (size_t)b*CN_ + pix0;

  const int scp = tid >> 5;
  const int spx = (tid & 31) << 2;
  const int e0 = tid*2, e1 = tid*2+1;
  const int wc0 = e0 >> 6, wo0 = e0 & 63;
  const int wc1 = e1 >> 6, wo1 = e1 & 63;

  { // stage slab 0
    const float4 xr = *(const float4*)(xb + (size_t)scp*N_ + spx);
    const float4 sr = *(const float4*)(sb + (size_t)scp*N_ + spx);
    const float a0 = vw[wo0*64 + wc0], a1 = vw[wo1*64 + wc1];
    const float f0 = fw[wo0*64 + wc0], f1 = fw[wo1*64 + wc1];
    *(float4*)&xsl[scp*128 + spx] = xr;
    *(float4*)&ssl[scp*128 + spx] = sr;
    wvl[e0] = a0; wvl[e1] = a1;
    wfl[e0] = f0; wfl[e1] = f1;
  }
  __syncthreads();

  const int lane = tid & 63, wv_ = tid >> 6;
  const int och  = 2*wv_ + (lane >> 5);
  const int ocb  = och*8;
  const int px4  = (lane & 31) << 2;

  float4 av[8], af[8];
  #pragma unroll
  for (int i = 0; i < 8; ++i) { av[i] = make_float4(0,0,0,0); af[i] = make_float4(0,0,0,0); }

  for (int ck = 0; ck < 8; ++ck) {
    const int cur = ck & 1, nxt = cur ^ 1;
    const float* xc = &xsl[cur*1024];
    const float* sc2 = &ssl[cur*1024];
    const float* wvc = &wvl[cur*512];
    const float* wfc = &wfl[cur*512];
    float4 xr, sr; float a0r, a1r, f0r, f1r;
    if (ck < 7) {
      const int c0n = (ck+1)*8;
      xr  = *(const float4*)(xb + (size_t)(c0n + scp)*N_ + spx);
      sr  = *(const float4*)(sb + (size_t)(c0n + scp)*N_ + spx);
      a0r = vw[wo0*64 + c0n + wc0]; a1r = vw[wo1*64 + c0n + wc1];
      f0r = fw[wo0*64 + c0n + wc0]; f1r = fw[wo1*64 + c0n + wc1];
    }
    #pragma unroll
    for (int cp = 0; cp < 8; ++cp) {
      const float4 xv = *(const float4*)&xc[cp*128 + px4];
      const float4 sv = *(const float4*)&sc2[cp*128 + px4];
      const float4 wa0 = *(const float4*)&wvc[cp*64 + ocb];
      const float4 wa1 = *(const float4*)&wvc[cp*64 + ocb + 4];
      const float4 wf0 = *(const float4*)&wfc[cp*64 + ocb];
      const float4 wf1 = *(const float4*)&wfc[cp*64 + ocb + 4];
      FMA4(av[0], wa0.x, xv); FMA4(av[1], wa0.y, xv);
      FMA4(av[2], wa0.z, xv); FMA4(av[3], wa0.w, xv);
      FMA4(av[4], wa1.x, xv); FMA4(av[5], wa1.y, xv);
      FMA4(av[6], wa1.z, xv); FMA4(av[7], wa1.w, xv);
      FMA4(af[0], wf0.x, sv); FMA4(af[1], wf0.y, sv);
      FMA4(af[2], wf0.z, sv); FMA4(af[3], wf0.w, sv);
      FMA4(af[4], wf1.x, sv); FMA4(af[5], wf1.y, sv);
      FMA4(af[6], wf1.z, sv); FMA4(af[7], wf1.w, sv);
    }
    if (ck < 7) {
      *(float4*)&xsl[nxt*1024 + scp*128 + spx] = xr;
      *(float4*)&ssl[nxt*1024 + scp*128 + spx] = sr;
      wvl[nxt*512 + e0] = a0r; wvl[nxt*512 + e1] = a1r;
      wfl[nxt*512 + e0] = f0r; wfl[nxt*512 + e1] = f1r;
    }
    __syncthreads();
  }

  // ---- V in registers (no global write) ----
  float4 v4[8];
  #pragma unroll
  for (int o = 0; o < 8; ++o) {
    const int oc = ocb + o;
    const float inv  = fbn[oc] / sqrtf(fbn[192+oc] + 1e-5f);
    const float beta = fbn[64+oc] - fbn[128+oc]*inv;
    const float bias = vb[oc];
    v4[o].x = av[o].x + bias + relu6f(fmaf(af[o].x, inv, beta));
    v4[o].y = av[o].y + bias + relu6f(fmaf(af[o].y, inv, beta));
    v4[o].z = av[o].z + bias + relu6f(fmaf(af[o].z, inv, beta));
    v4[o].w = av[o].w + bias + relu6f(fmaf(af[o].w, inv, beta));
  }

  // ---- stage K tile [m=8][px=128] into reused xsl ----
  // (all threads passed the loop's final barrier; no xsl reads remain)
  const float* Kb = Kq + (size_t)b*MN_ + pix0;
  for (int idx = tid; idx < 1024; idx += 256)
    xsl[idx] = Kb[(size_t)(idx >> 7)*N_ + (idx & 127)];
  __syncthreads();

  // ---- partial KV: dot over this thread's 4 px, reduce over 32-lane half ----
  const int l31 = lane & 31;
  #pragma unroll
  for (int half = 0; half < 2; ++half) {
    float p[32];                        // p[m2*8+o], m = half*4+m2
    #pragma unroll
    for (int m2 = 0; m2 < 4; ++m2) {
      const float4 kv4 = *(const float4*)&xsl[(half*4+m2)*128 + px4];
      #pragma unroll
      for (int o = 0; o < 8; ++o) {
        float t = kv4.x*v4[o].x;
        t = fmaf(kv4.y, v4[o].y, t);
        t = fmaf(kv4.z, v4[o].z, t);
        t = fmaf(kv4.w, v4[o].w, t);
        p[m2*8+o] = t;
      }
    }
    // value-halving butterfly: 32 values over 32 lanes -> 1 value/lane
    int nv = 32;
    #pragma unroll
    for (int mask = 1; mask <= 16; mask <<= 1) {
      nv >>= 1;
      const bool hi = (l31 & mask) != 0;
      #pragma unroll
      for (int i = 0; i < nv; ++i) {
        const float mine = hi ? p[i] : p[i+nv];
        const float th = __shfl_xor(mine, mask);
        p[i] = (hi ? p[i+nv] : p[i]) + th;
      }
    }
    // lane l31 holds the full 128-px sum for value-index j (bit-reversed lane)
    const int j = 16*(l31 & 1) + 8*((l31 >> 1) & 1) + 4*((l31 >> 2) & 1)
                + 2*((l31 >> 3) & 1) + ((l31 >> 4) & 1);
    const int m = half*4 + (j >> 3);
    const int o = j & 7;
    atomicAdd(&KV[b*512 + m*64 + ocb + o], p[0]);
  }
}

// ---------------------------------------------------------------------------
// K5: Q on the fly; out = x + gamma * (Q^T KV) / (Q^T (Ksum+eps))
// NEW: no 64KB x staging (was capping at 2 blocks/CU). x is L3-resident
// (k_vkv just read it); both passes read it coalesced from global.
// ---------------------------------------------------------------------------
__global__ __launch_bounds__(256) void k_out(const float* __restrict__ x,
                                             const float* __restrict__ qw,
                                             const float* __restrict__ qb,
                                             const float* __restrict__ gamma,
                                             const float* __restrict__ KV,
                                             const float* __restrict__ Ksum,
                                             float* __restrict__ out)
{
  __shared__ __align__(16) float kvt[64*8];    // kvt[c][m]
  __shared__ __align__(16) float wqt[64*8];    // wqt[c][m]
  __shared__ float ksl[8];
  const int tid = threadIdx.x;
  const int b  = blockIdx.x / 196;
  const int pg = blockIdx.x % 196;
  const int pix0 = pg*256;
  const float* xb = x + (size_t)b*CN_ + pix0 + tid;

  for (int idx = tid; idx < 512; idx += 256) {
    const int m = idx >> 6, c = idx & 63;
    kvt[c*8 + m] = KV[b*512 + idx];
    wqt[c*8 + m] = qw[idx];
  }
  if (tid < 8) ksl[tid] = Ksum[b*8 + tid] + 1e-6f;
  __syncthreads();

  float q[8] = {0,0,0,0,0,0,0,0};
  #pragma unroll 8
  for (int c = 0; c < 64; ++c) {
    const float xv = xb[(size_t)c*N_];
    const float4 w0 = *(const float4*)&wqt[c*8];
    const float4 w1 = *(const float4*)&wqt[c*8+4];
    q[0] = fmaf(w0.x, xv, q[0]);
    q[1] = fmaf(w0.y, xv, q[1]);
    q[2] = fmaf(w0.z, xv, q[2]);
    q[3] = fmaf(w0.w, xv, q[3]);
    q[4] = fmaf(w1.x, xv, q[4]);
    q[5] = fmaf(w1.y, xv, q[5]);
    q[6] = fmaf(w1.z, xv, q[6]);
    q[7] = fmaf(w1.w, xv, q[7]);
  }
  float den = 0.0f;
  #pragma unroll
  for (int m = 0; m < 8; ++m) {
    q[m] = softplusf(q[m] + qb[m]);
    den  = fmaf(q[m], ksl[m], den);
  }
  const float sc = gamma[0] / den;

  float* ob = out + (size_t)b*CN_ + pix0 + tid;
  #pragma unroll 8
  for (int c = 0; c < 64; ++c) {
    const float4 k0 = *(const float4*)&kvt[c*8];
    const float4 k1 = *(const float4*)&kvt[c*8+4];
    float wv;
    wv = q[0]*k0.x;
    wv = fmaf(q[1], k0.y, wv);
    wv = fmaf(q[2], k0.z, wv);
    wv = fmaf(q[3], k0.w, wv);
    wv = fmaf(q[4], k1.x, wv);
    wv = fmaf(q[5], k1.y, wv);
    wv = fmaf(q[6], k1.z, wv);
    wv = fmaf(q[7], k1.w, wv);
    ob[(size_t)c*N_] = fmaf(sc, wv, xb[(size_t)c*N_]);
  }
}

// ---------------------------------------------------------------------------
extern "C" void kernel_launch(void* const* d_in, const int* in_sizes, int n_in,
                              void* d_out, int out_size, void* d_ws, size_t ws_size,
                              hipStream_t stream) {
  const float* x      = (const float*)d_in[0];
  const float* gamma  = (const float*)d_in[1];
  const float* q_w    = (const float*)d_in[2];
  const float* q_b    = (const float*)d_in[3];
  const float* k_w    = (const float*)d_in[4];
  const float* k_b    = (const float*)d_in[5];
  const float* v_w    = (const float*)d_in[6];
  const float* v_b    = (const float*)d_in[7];
  const float* fc1_w  = (const float*)d_in[8];
  const float* fc1_bn = (const float*)d_in[9];
  const float* c1_w   = (const float*)d_in[10];
  const float* c1_bn  = (const float*)d_in[11];
  const float* c2_w   = (const float*)d_in[12];
  const float* c2_bn  = (const float*)d_in[13];
  const float* fc2_w  = (const float*)d_in[14];
  const float* fc2_bn = (const float*)d_in[15];
  float* outp = (float*)d_out;

  float* ws   = (float*)d_ws;
  float* bufA = ws;                        // h
  float* bufS = ws + (size_t)BCN_;
  float* bufK = ws + (size_t)2*BCN_;
  float* kv   = ws + (size_t)2*BCN_ + BMN_;
  float* ksum = kv + 2048;

  hipMemsetAsync(kv, 0, (2048 + 32)*sizeof(float), stream);

  k_fc1k<<<dim3(B_*392), dim3(256), 0, stream>>>(x, fc1_w, fc1_bn, k_w, k_b, bufA, bufK, ksum);
  k_dw  <<<dim3(B_*C_*49), dim3(256), 0, stream>>>(bufA, c1_w, c2_w, c1_bn, c2_bn, bufS);
  k_vkv <<<dim3(B_*392), dim3(256), 0, stream>>>(x, bufS, v_w, v_b, fc2_w, fc2_bn, bufK, kv);
  k_out <<<dim3(B_*196), dim3(256), 0, stream>>>(x, q_w, q_b, gamma, kv, ksum, outp);
}

// Round 2
// 332.634 us; speedup vs baseline: 3.4929x; 3.4929x over previous
//
#include <hip/hip_runtime.h>
#include <math.h>

#define B_ 4
#define C_ 64
#define M_ 8
#define H_ 224
#define W_ 224
#define N_ (H_*W_)        // 50176
#define CN_ (C_*N_)       // 3211264
#define MN_ (M_*N_)       // 401408
#define BCN_ (B_*CN_)
#define BMN_ (B_*MN_)
#define NPG_ 392          // pixel groups of 128 per batch image

__device__ __forceinline__ float relu6f(float v){ return fminf(fmaxf(v,0.0f),6.0f); }
__device__ __forceinline__ float softplusf(float v){
  return v > 0.0f ? v + log1pf(expf(-v)) : log1pf(expf(v));
}

#define FMA4(A, W, X) { A.x = fmaf((W), (X).x, A.x); A.y = fmaf((W), (X).y, A.y); \
                        A.z = fmaf((W), (X).z, A.z); A.w = fmaf((W), (X).w, A.w); }

// ---------------------------------------------------------------------------
// K1: h = relu6(bn(conv1x1(x))) AND K = softplus(conv1x1(x)+kb) AND Ksum part
// 128-px tile, 64 oc/block. c in 8-wide slabs double-buffered in LDS.
// Ksum: per-block partial STORE (no atomics — round-1 showed contended
// device atomics serialize at ~70ns/RMW at the coherence point).
// ---------------------------------------------------------------------------
__global__ __launch_bounds__(256) void k_fc1k(const float* __restrict__ x,
                                              const float* __restrict__ w,
                                              const float* __restrict__ bn,
                                              const float* __restrict__ kw,
                                              const float* __restrict__ kb,
                                              float* __restrict__ h,
                                              float* __restrict__ Kq,
                                              float* __restrict__ ks_part)
{
  __shared__ float xsl[2*1024];   // [buf][c'(8)][px(128)]
  __shared__ float wl [2*512];    // [buf][c'(8)][oc(64)]
  __shared__ float kt [512];      // [c(64)][m(8)]
  const int tid  = threadIdx.x;
  const int b    = blockIdx.x / NPG_;
  const int pg   = blockIdx.x % NPG_;
  const int pix0 = pg*128;
  const float* xb = x + (size_t)b*CN_ + pix0;

  for (int idx = tid; idx < 512; idx += 256) {
    const int c = idx >> 3, m = idx & 7;
    kt[idx] = kw[m*64 + c];
  }

  // staging roles
  const int scp = tid >> 5;            // c' 0..7
  const int spx = (tid & 31) << 2;     // px 0,4,..,124
  const int e0 = tid*2, e1 = tid*2+1;
  const int wc0 = e0 >> 6, wo0 = e0 & 63;
  const int wc1 = e1 >> 6, wo1 = e1 & 63;

  { // stage slab 0
    const float4 xr = *(const float4*)(xb + (size_t)scp*N_ + spx);
    const float w0r = w[wo0*64 + wc0];
    const float w1r = w[wo1*64 + wc1];
    *(float4*)&xsl[scp*128 + spx] = xr;
    wl[e0] = w0r; wl[e1] = w1r;
  }
  __syncthreads();

  const int lane = tid & 63, wv_ = tid >> 6;
  const int och  = 2*wv_ + (lane >> 5);   // 0..7
  const int ocb  = och*8;
  const int px4  = (lane & 31) << 2;

  float4 ah[8];
  float4 ak = {0,0,0,0};
  #pragma unroll
  for (int i = 0; i < 8; ++i) ah[i] = make_float4(0.f,0.f,0.f,0.f);

  for (int ck = 0; ck < 8; ++ck) {
    const int cur = ck & 1, nxt = cur ^ 1;
    const float* xc = &xsl[cur*1024];
    const float* wc = &wl[cur*512];
    float4 xr; float w0r, w1r;
    if (ck < 7) {                       // issue next slab's global loads now
      const int c0n = (ck+1)*8;
      xr  = *(const float4*)(xb + (size_t)(c0n + scp)*N_ + spx);
      w0r = w[wo0*64 + c0n + wc0];
      w1r = w[wo1*64 + c0n + wc1];
    }
    #pragma unroll
    for (int cp = 0; cp < 8; ++cp) {
      const float4 xv = *(const float4*)&xc[cp*128 + px4];
      const float4 w0 = *(const float4*)&wc[cp*64 + ocb];
      const float4 w1 = *(const float4*)&wc[cp*64 + ocb + 4];
      const float kvw = kt[(ck*8+cp)*8 + och];
      FMA4(ah[0], w0.x, xv); FMA4(ah[1], w0.y, xv);
      FMA4(ah[2], w0.z, xv); FMA4(ah[3], w0.w, xv);
      FMA4(ah[4], w1.x, xv); FMA4(ah[5], w1.y, xv);
      FMA4(ah[6], w1.z, xv); FMA4(ah[7], w1.w, xv);
      FMA4(ak, kvw, xv);
    }
    if (ck < 7) {                       // park staged regs into next buffer
      *(float4*)&xsl[nxt*1024 + scp*128 + spx] = xr;
      wl[nxt*512 + e0] = w0r; wl[nxt*512 + e1] = w1r;
    }
    __syncthreads();
  }

  float* hb = h + (size_t)b*CN_ + pix0 + px4;
  #pragma unroll
  for (int o = 0; o < 8; ++o) {
    const int oc = ocb + o;
    const float inv  = bn[oc] / sqrtf(bn[192+oc] + 1e-5f);
    const float beta = bn[64+oc] - bn[128+oc]*inv;
    float4 o4;
    o4.x = relu6f(fmaf(ah[o].x, inv, beta));
    o4.y = relu6f(fmaf(ah[o].y, inv, beta));
    o4.z = relu6f(fmaf(ah[o].z, inv, beta));
    o4.w = relu6f(fmaf(ah[o].w, inv, beta));
    *(float4*)(hb + (size_t)oc*N_) = o4;
  }
  { // K row m = och, plus Ksum per-block partial (sum over 128 px)
    const float kbm = kb[och];
    float4 q;
    q.x = softplusf(ak.x + kbm); q.y = softplusf(ak.y + kbm);
    q.z = softplusf(ak.z + kbm); q.w = softplusf(ak.w + kbm);
    *(float4*)(Kq + (size_t)b*MN_ + (size_t)och*N_ + pix0 + px4) = q;
    float ss = (q.x + q.y) + (q.z + q.w);
    ss += __shfl_xor(ss, 1);
    ss += __shfl_xor(ss, 2);
    ss += __shfl_xor(ss, 4);
    ss += __shfl_xor(ss, 8);
    ss += __shfl_xor(ss, 16);
    if ((lane & 31) == 0)
      ks_part[(size_t)(b*NPG_ + pg)*8 + och] = ss;   // plain store
  }
}

// ---------------------------------------------------------------------------
// K2: s = relu6(bn1(dw5x5(h))) + relu6(bn2(dw3x3(h)))   32x32 tile per (b,c)
// ---------------------------------------------------------------------------
__global__ __launch_bounds__(256) void k_dw(const float* __restrict__ h,
                                            const float* __restrict__ w5,
                                            const float* __restrict__ w3,
                                            const float* __restrict__ bn1,
                                            const float* __restrict__ bn2,
                                            float* __restrict__ s)
{
  __shared__ float tile[36*37];
  const int tid = threadIdx.x;
  const int blk = blockIdx.x;              // B*C*49
  const int t   = blk % 49;
  const int bc  = blk / 49;
  const int c   = bc & 63;
  const int tx0 = (t % 7) * 32;
  const int ty0 = (t / 7) * 32;
  const float* hb = h + (size_t)bc * N_;

  for (int idx = tid; idx < 1296; idx += 256) {
    const int ly = idx / 36, lx = idx - ly*36;
    const int gy = ty0 + ly - 2, gx = tx0 + lx - 2;
    float v = 0.0f;
    if (gy >= 0 && gy < H_ && gx >= 0 && gx < W_) v = hb[gy*W_ + gx];
    tile[ly*37 + lx] = v;
  }
  __syncthreads();

  float w5r[25], w3r[9];
  #pragma unroll
  for (int i = 0; i < 25; ++i) w5r[i] = w5[c*25 + i];
  #pragma unroll
  for (int i = 0; i < 9; ++i)  w3r[i] = w3[c*9 + i];
  const float inv1 = bn1[c] / sqrtf(bn1[192+c] + 1e-5f);
  const float bet1 = bn1[64+c] - bn1[128+c]*inv1;
  const float inv2 = bn2[c] / sqrtf(bn2[192+c] + 1e-5f);
  const float bet2 = bn2[64+c] - bn2[128+c]*inv2;

  const int ty  = tid >> 3;
  const int tx4 = (tid & 7) << 2;
  float a5[4] = {0,0,0,0}, a3[4] = {0,0,0,0};
  #pragma unroll
  for (int dy = 0; dy < 5; ++dy) {
    float r[8];
    #pragma unroll
    for (int i = 0; i < 8; ++i) r[i] = tile[(ty+dy)*37 + tx4 + i];
    #pragma unroll
    for (int dx = 0; dx < 5; ++dx) {
      const float wv = w5r[dy*5+dx];
      #pragma unroll
      for (int p = 0; p < 4; ++p) a5[p] = fmaf(wv, r[p+dx], a5[p]);
    }
    if (dy >= 1 && dy <= 3) {
      #pragma unroll
      for (int dx = 1; dx <= 3; ++dx) {
        const float wv = w3r[(dy-1)*3+(dx-1)];
        #pragma unroll
        for (int p = 0; p < 4; ++p) a3[p] = fmaf(wv, r[p+dx], a3[p]);
      }
    }
  }
  float* sb = s + (size_t)bc * N_ + (ty0+ty)*W_ + tx0 + tx4;
  float4 o4;
  o4.x = relu6f(fmaf(a5[0],inv1,bet1)) + relu6f(fmaf(a3[0],inv2,bet2));
  o4.y = relu6f(fmaf(a5[1],inv1,bet1)) + relu6f(fmaf(a3[1],inv2,bet2));
  o4.z = relu6f(fmaf(a5[2],inv1,bet1)) + relu6f(fmaf(a3[2],inv2,bet2));
  o4.w = relu6f(fmaf(a5[3],inv1,bet1)) + relu6f(fmaf(a3[3],inv2,bet2));
  *(float4*)sb = o4;
}

// ---------------------------------------------------------------------------
// K3 (fused): V = conv1x1(x,v_w)+v_b + relu6(bn(conv1x1(s,fc2_w))) in regs,
// then per-block KV partial: for each m, 8-value halving butterfly over the
// 32-lane half (9 shuffles, only p[8] live -> low VGPR), deposit into free
// LDS (wvl), one coalesced 2KB store per block. NO atomics.
// ---------------------------------------------------------------------------
__global__ __launch_bounds__(256) void k_vkv(const float* __restrict__ x,
                                             const float* __restrict__ s,
                                             const float* __restrict__ vw,
                                             const float* __restrict__ vb,
                                             const float* __restrict__ fw,
                                             const float* __restrict__ fbn,
                                             const float* __restrict__ Kq,
                                             float* __restrict__ kv_part)
{
  __shared__ float xsl[2*1024];
  __shared__ float ssl[2*1024];
  __shared__ float wvl[2*512];
  __shared__ float wfl[2*512];
  const int tid  = threadIdx.x;
  const int b    = blockIdx.x / NPG_;
  const int pg   = blockIdx.x % NPG_;
  const int pix0 = pg*128;
  const float* xb = x + (size_t)b*CN_ + pix0;
  const float* sb = s + (size_t)b*CN_ + pix0;

  const int scp = tid >> 5;
  const int spx = (tid & 31) << 2;
  const int e0 = tid*2, e1 = tid*2+1;
  const int wc0 = e0 >> 6, wo0 = e0 & 63;
  const int wc1 = e1 >> 6, wo1 = e1 & 63;

  { // stage slab 0
    const float4 xr = *(const float4*)(xb + (size_t)scp*N_ + spx);
    const float4 sr = *(const float4*)(sb + (size_t)scp*N_ + spx);
    const float a0 = vw[wo0*64 + wc0], a1 = vw[wo1*64 + wc1];
    const float f0 = fw[wo0*64 + wc0], f1 = fw[wo1*64 + wc1];
    *(float4*)&xsl[scp*128 + spx] = xr;
    *(float4*)&ssl[scp*128 + spx] = sr;
    wvl[e0] = a0; wvl[e1] = a1;
    wfl[e0] = f0; wfl[e1] = f1;
  }
  __syncthreads();

  const int lane = tid & 63, wv_ = tid >> 6;
  const int och  = 2*wv_ + (lane >> 5);
  const int ocb  = och*8;
  const int px4  = (lane & 31) << 2;

  float4 av[8], af[8];
  #pragma unroll
  for (int i = 0; i < 8; ++i) { av[i] = make_float4(0,0,0,0); af[i] = make_float4(0,0,0,0); }

  for (int ck = 0; ck < 8; ++ck) {
    const int cur = ck & 1, nxt = cur ^ 1;
    const float* xc = &xsl[cur*1024];
    const float* sc2 = &ssl[cur*1024];
    const float* wvc = &wvl[cur*512];
    const float* wfc = &wfl[cur*512];
    float4 xr, sr; float a0r, a1r, f0r, f1r;
    if (ck < 7) {
      const int c0n = (ck+1)*8;
      xr  = *(const float4*)(xb + (size_t)(c0n + scp)*N_ + spx);
      sr  = *(const float4*)(sb + (size_t)(c0n + scp)*N_ + spx);
      a0r = vw[wo0*64 + c0n + wc0]; a1r = vw[wo1*64 + c0n + wc1];
      f0r = fw[wo0*64 + c0n + wc0]; f1r = fw[wo1*64 + c0n + wc1];
    }
    #pragma unroll
    for (int cp = 0; cp < 8; ++cp) {
      const float4 xv = *(const float4*)&xc[cp*128 + px4];
      const float4 sv = *(const float4*)&sc2[cp*128 + px4];
      const float4 wa0 = *(const float4*)&wvc[cp*64 + ocb];
      const float4 wa1 = *(const float4*)&wvc[cp*64 + ocb + 4];
      const float4 wf0 = *(const float4*)&wfc[cp*64 + ocb];
      const float4 wf1 = *(const float4*)&wfc[cp*64 + ocb + 4];
      FMA4(av[0], wa0.x, xv); FMA4(av[1], wa0.y, xv);
      FMA4(av[2], wa0.z, xv); FMA4(av[3], wa0.w, xv);
      FMA4(av[4], wa1.x, xv); FMA4(av[5], wa1.y, xv);
      FMA4(av[6], wa1.z, xv); FMA4(av[7], wa1.w, xv);
      FMA4(af[0], wf0.x, sv); FMA4(af[1], wf0.y, sv);
      FMA4(af[2], wf0.z, sv); FMA4(af[3], wf0.w, sv);
      FMA4(af[4], wf1.x, sv); FMA4(af[5], wf1.y, sv);
      FMA4(af[6], wf1.z, sv); FMA4(af[7], wf1.w, sv);
    }
    if (ck < 7) {
      *(float4*)&xsl[nxt*1024 + scp*128 + spx] = xr;
      *(float4*)&ssl[nxt*1024 + scp*128 + spx] = sr;
      wvl[nxt*512 + e0] = a0r; wvl[nxt*512 + e1] = a1r;
      wfl[nxt*512 + e0] = f0r; wfl[nxt*512 + e1] = f1r;
    }
    __syncthreads();
  }

  // ---- V in registers (no global write); av/af die here, v4 reuses regs ----
  float4 v4[8];
  #pragma unroll
  for (int o = 0; o < 8; ++o) {
    const int oc = ocb + o;
    const float inv  = fbn[oc] / sqrtf(fbn[192+oc] + 1e-5f);
    const float beta = fbn[64+oc] - fbn[128+oc]*inv;
    const float bias = vb[oc];
    v4[o].x = av[o].x + bias + relu6f(fmaf(af[o].x, inv, beta));
    v4[o].y = av[o].y + bias + relu6f(fmaf(af[o].y, inv, beta));
    v4[o].z = av[o].z + bias + relu6f(fmaf(af[o].z, inv, beta));
    v4[o].w = av[o].w + bias + relu6f(fmaf(af[o].w, inv, beta));
  }

  // ---- stage K tile [m=8][px=128] into reused xsl ----
  const float* Kb = Kq + (size_t)b*MN_ + pix0;
  for (int idx = tid; idx < 1024; idx += 256)
    xsl[idx] = Kb[(size_t)(idx >> 7)*N_ + (idx & 127)];
  __syncthreads();

  // ---- per-m: 8 dots, 8-value halving butterfly over 32-lane half ----
  const int l31 = lane & 31;
  const int j   = 4*(l31 & 1) + 2*((l31 >> 1) & 1) + ((l31 >> 2) & 1);
  #pragma unroll
  for (int m = 0; m < 8; ++m) {
    const float4 kv4 = *(const float4*)&xsl[m*128 + px4];
    float p[8];
    #pragma unroll
    for (int o = 0; o < 8; ++o) {
      float t = kv4.x*v4[o].x;
      t = fmaf(kv4.y, v4[o].y, t);
      t = fmaf(kv4.z, v4[o].z, t);
      t = fmaf(kv4.w, v4[o].w, t);
      p[o] = t;
    }
    int nv = 8;
    #pragma unroll
    for (int mask = 1; mask <= 4; mask <<= 1) {
      nv >>= 1;
      const bool hi = (l31 & mask) != 0;
      #pragma unroll
      for (int i = 0; i < nv; ++i) {
        const float mine = hi ? p[i] : p[i+nv];
        const float th = __shfl_xor(mine, mask);
        p[i] = (hi ? p[i+nv] : p[i]) + th;
      }
    }
    p[0] += __shfl_xor(p[0], 8);
    p[0] += __shfl_xor(p[0], 16);
    // lane l31 (<8) holds full 128-px sum for value j (3-bit bit-reversal)
    if (l31 < 8) wvl[m*64 + ocb + j] = p[0];
  }
  __syncthreads();

  // ---- coalesced 2KB dump of the block's KV partial ----
  float* kp = kv_part + (size_t)(b*NPG_ + pg)*512;
  kp[tid]       = wvl[tid];
  kp[tid + 256] = wvl[tid + 256];
}

// ---------------------------------------------------------------------------
// K4: reduce per-block partials -> KV[b,512], Ksum[b,8]. 3.2MB total reads.
// ---------------------------------------------------------------------------
__global__ __launch_bounds__(256) void k_red(const float* __restrict__ kv_part,
                                             const float* __restrict__ ks_part,
                                             float* __restrict__ KV,
                                             float* __restrict__ Ksum)
{
  __shared__ float red[4][64];
  __shared__ float rks[256];
  const int blk = blockIdx.x;          // 32 blocks: b = blk>>3, seg = blk&7
  const int b = blk >> 3, seg = blk & 7;
  const int t = threadIdx.x;
  const int i = seg*64 + (t & 63);
  const int sl = t >> 6;               // 0..3
  const float* base = kv_part + (size_t)b*NPG_*512 + i;
  float a = 0.0f;
  for (int g = sl; g < NPG_; g += 4) a += base[(size_t)g*512];
  red[sl][t & 63] = a;
  __syncthreads();
  if (t < 64)
    KV[b*512 + seg*64 + t] = (red[0][t] + red[1][t]) + (red[2][t] + red[3][t]);

  if (seg == 0) {
    const int m = t & 7, g0 = t >> 3;  // 32 slices per m
    float s2 = 0.0f;
    for (int g = g0; g < NPG_; g += 32)
      s2 += ks_part[(size_t)b*NPG_*8 + g*8 + m];
    rks[t] = s2;
    __syncthreads();
    if (t < 8) {
      float s3 = 0.0f;
      #pragma unroll
      for (int j2 = 0; j2 < 32; ++j2) s3 += rks[j2*8 + t];
      Ksum[b*8 + t] = s3;
    }
  }
}

// ---------------------------------------------------------------------------
// K5: Q on the fly; out = x + gamma * (Q^T KV) / (Q^T (Ksum+eps))
// ---------------------------------------------------------------------------
__global__ __launch_bounds__(256) void k_out(const float* __restrict__ x,
                                             const float* __restrict__ qw,
                                             const float* __restrict__ qb,
                                             const float* __restrict__ gamma,
                                             const float* __restrict__ KV,
                                             const float* __restrict__ Ksum,
                                             float* __restrict__ out)
{
  __shared__ __align__(16) float kvt[64*8];    // kvt[c][m]
  __shared__ __align__(16) float wqt[64*8];    // wqt[c][m]
  __shared__ float ksl[8];
  const int tid = threadIdx.x;
  const int b  = blockIdx.x / 196;
  const int pg = blockIdx.x % 196;
  const int pix0 = pg*256;
  const float* xb = x + (size_t)b*CN_ + pix0 + tid;

  for (int idx = tid; idx < 512; idx += 256) {
    const int m = idx >> 6, c = idx & 63;
    kvt[c*8 + m] = KV[b*512 + idx];
    wqt[c*8 + m] = qw[idx];
  }
  if (tid < 8) ksl[tid] = Ksum[b*8 + tid] + 1e-6f;
  __syncthreads();

  float q[8] = {0,0,0,0,0,0,0,0};
  #pragma unroll 8
  for (int c = 0; c < 64; ++c) {
    const float xv = xb[(size_t)c*N_];
    const float4 w0 = *(const float4*)&wqt[c*8];
    const float4 w1 = *(const float4*)&wqt[c*8+4];
    q[0] = fmaf(w0.x, xv, q[0]);
    q[1] = fmaf(w0.y, xv, q[1]);
    q[2] = fmaf(w0.z, xv, q[2]);
    q[3] = fmaf(w0.w, xv, q[3]);
    q[4] = fmaf(w1.x, xv, q[4]);
    q[5] = fmaf(w1.y, xv, q[5]);
    q[6] = fmaf(w1.z, xv, q[6]);
    q[7] = fmaf(w1.w, xv, q[7]);
  }
  float den = 0.0f;
  #pragma unroll
  for (int m = 0; m < 8; ++m) {
    q[m] = softplusf(q[m] + qb[m]);
    den  = fmaf(q[m], ksl[m], den);
  }
  const float sc = gamma[0] / den;

  float* ob = out + (size_t)b*CN_ + pix0 + tid;
  #pragma unroll 8
  for (int c = 0; c < 64; ++c) {
    const float4 k0 = *(const float4*)&kvt[c*8];
    const float4 k1 = *(const float4*)&kvt[c*8+4];
    float wv;
    wv = q[0]*k0.x;
    wv = fmaf(q[1], k0.y, wv);
    wv = fmaf(q[2], k0.z, wv);
    wv = fmaf(q[3], k0.w, wv);
    wv = fmaf(q[4], k1.x, wv);
    wv = fmaf(q[5], k1.y, wv);
    wv = fmaf(q[6], k1.z, wv);
    wv = fmaf(q[7], k1.w, wv);
    ob[(size_t)c*N_] = fmaf(sc, wv, xb[(size_t)c*N_]);
  }
}

// ---------------------------------------------------------------------------
extern "C" void kernel_launch(void* const* d_in, const int* in_sizes, int n_in,
                              void* d_out, int out_size, void* d_ws, size_t ws_size,
                              hipStream_t stream) {
  const float* x      = (const float*)d_in[0];
  const float* gamma  = (const float*)d_in[1];
  const float* q_w    = (const float*)d_in[2];
  const float* q_b    = (const float*)d_in[3];
  const float* k_w    = (const float*)d_in[4];
  const float* k_b    = (const float*)d_in[5];
  const float* v_w    = (const float*)d_in[6];
  const float* v_b    = (const float*)d_in[7];
  const float* fc1_w  = (const float*)d_in[8];
  const float* fc1_bn = (const float*)d_in[9];
  const float* c1_w   = (const float*)d_in[10];
  const float* c1_bn  = (const float*)d_in[11];
  const float* c2_w   = (const float*)d_in[12];
  const float* c2_bn  = (const float*)d_in[13];
  const float* fc2_w  = (const float*)d_in[14];
  const float* fc2_bn = (const float*)d_in[15];
  float* outp = (float*)d_out;

  float* ws      = (float*)d_ws;
  float* bufA    = ws;                         // h; dead after k_dw
  float* bufS    = ws + (size_t)BCN_;
  float* bufK    = ws + (size_t)2*BCN_;
  float* ks_part = ws + (size_t)2*BCN_ + BMN_;             // 4*392*8
  float* kv      = ks_part + (size_t)B_*NPG_*8;            // 2048
  float* ksum    = kv + 2048;                              // 32
  float* kv_part = bufA;                       // alias h (4*392*512 floats)

  k_fc1k<<<dim3(B_*NPG_), dim3(256), 0, stream>>>(x, fc1_w, fc1_bn, k_w, k_b, bufA, bufK, ks_part);
  k_dw  <<<dim3(B_*C_*49), dim3(256), 0, stream>>>(bufA, c1_w, c2_w, c1_bn, c2_bn, bufS);
  k_vkv <<<dim3(B_*NPG_), dim3(256), 0, stream>>>(x, bufS, v_w, v_b, fc2_w, fc2_bn, bufK, kv_part);
  k_red <<<dim3(32), dim3(256), 0, stream>>>(kv_part, ks_part, kv, ksum);
  k_out <<<dim3(B_*196), dim3(256), 0, stream>>>(x, q_w, q_b, gamma, kv, ksum, outp);
}